// Round 15
// baseline (201.006 us; speedup 1.0000x reference)
//
#include <hip/hip_runtime.h>

typedef _Float16 f16;
typedef f16 f16x4 __attribute__((ext_vector_type(4)));
typedef f16 f16x8 __attribute__((ext_vector_type(8)));
typedef float f32x4 __attribute__((ext_vector_type(4)));

#define NB 1024
#define NF 64
#define ND 256
#define KWIN 85
#define INDIM 32768
#define OUTC 8192
#define MAXFIX 32
#define FKB 64  // k-chunks per flagged row in fixup pass 1 (512 k each)
// W pre-scaled by 256; lo-parts scaled by 2048; undone in f32 epilogues.
#define WSCALE 256.0f
#define LSCALE 2048.0f
#define INV_WS (1.0f / 256.0f)
#define INV_LS (1.0f / 2048.0f)

__device__ __forceinline__ int swz4(int row, int slot) { return slot ^ ((row ^ (row >> 2)) & 3); }
__device__ __forceinline__ int swz8(int row, int slot) { return slot ^ ((row ^ (row >> 3)) & 7); }

__device__ __forceinline__ void gl2lds16(const void* g, void* l) {
  __builtin_amdgcn_global_load_lds((const __attribute__((address_space(1))) void*)g,
                                   (__attribute__((address_space(3))) void*)l, 16, 0, 0);
}

// ---------------- transpose + fp16 hi/lo-scaled split: dst[c][r] = split(src[r][c]*256) ----------------
__global__ __launch_bounds__(256) void transpose_split(const float* __restrict__ src,
                                                       f16* __restrict__ dhi, f16* __restrict__ dlo,
                                                       int R, int C) {
  __shared__ float tile[64][65];
  int t = threadIdx.x;
  int tiles_c = C >> 6;
  int tr = blockIdx.x / tiles_c, tc = blockIdx.x - tr * tiles_c;
  size_t r0 = (size_t)tr << 6;
  int c0 = tc << 6;
  int rr = t >> 4, cc = (t & 15) << 2;
#pragma unroll
  for (int p = 0; p < 4; ++p) {
    const float4 v = *(const float4*)(src + (r0 + (p << 4) + rr) * C + c0 + cc);
    tile[(p << 4) + rr][cc + 0] = v.x;
    tile[(p << 4) + rr][cc + 1] = v.y;
    tile[(p << 4) + rr][cc + 2] = v.z;
    tile[(p << 4) + rr][cc + 3] = v.w;
  }
  __syncthreads();
  int n = t >> 2, kq = t & 3;
  alignas(16) f16 hv[16];
  alignas(16) f16 lv[16];
#pragma unroll
  for (int e = 0; e < 16; ++e) {
    float x = tile[(kq << 4) + e][n] * WSCALE;
    f16 h = (f16)x;
    hv[e] = h;
    lv[e] = (f16)((x - (float)h) * LSCALE);
  }
  size_t ob = (size_t)(c0 + n) * (size_t)R + r0 + (kq << 4);
  *(f16x8*)(dhi + ob)     = *(const f16x8*)&hv[0];
  *(f16x8*)(dhi + ob + 8) = *(const f16x8*)&hv[8];
  *(f16x8*)(dlo + ob)     = *(const f16x8*)&lv[0];
  *(f16x8*)(dlo + ob + 8) = *(const f16x8*)&lv[8];
}

// ---------------- GEMM1: BM=256 x BN=128, 1024 thr / 16 waves, 256 blocks (1/CU); fp16x3 dual-acc ----------------
// partial[chunk] = x[:, chunk*1024:+1024] @ W1[chunk rows]
// staged bytes = 134MB*(256/128) + 33.5MB*(1024/256) = 402 MB (vs 536 at r14).
// Same 16 waves/CU as r14 (one 1024-thr block vs two 512-thr) — tests rate(blocks) vs rate(waves).
// decode: chunk = bid&31 -> bid%8 = chunk%8 -> a chunk's 8 blocks share one XCD's L2.
__global__ __launch_bounds__(1024, 4) void gemm1_kernel(const float* __restrict__ meanp, const float* __restrict__ varp,
                                                        const f16* __restrict__ w1h, const f16* __restrict__ w1l,
                                                        float* __restrict__ partial) {
  __shared__ alignas(16) f16 sAh[256 * 32], sAl[256 * 32];  // 16 KB each
  __shared__ alignas(16) f16 sBh[128 * 32], sBl[128 * 32];  // 8 KB each (48 KB total)
  int t = threadIdx.x;
  int chunk = blockIdx.x & 31;
  int nb = (blockIdx.x >> 5) & 1;
  int rb = blockIdx.x >> 6;
  int bm = rb << 8, bn = nb << 7;
  int wid = t >> 6, lane = t & 63, lr = lane & 15, lk = lane >> 4;
  int wr = wid >> 1, wc = wid & 1;  // 8 row-groups x 2 col-groups; wave tile 32x64
  f32x4 acc0[2][4] = {};
  f32x4 acc1[2][4] = {};
  int ar = t >> 3, ac4 = t & 7;  // A: rows ar, ar+128; 8 k-slots

  for (int kk = 0; kk < 32; ++kk) {
    int gk = (chunk << 10) + (kk << 5);
    // ---- stage B: waves 0-7 -> sBh, waves 8-15 -> sBl (1 KB per wave; involutive swz4 source pre-swizzle)
    {
      int w8 = wid & 7;
      int col = (w8 << 4) + (lane >> 2), slot = lane & 3;
      size_t go = (size_t)(bn + col) * INDIM + (size_t)gk + (size_t)(swz4(col, slot) << 3);
      if (wid < 8) gl2lds16(w1h + go, (char*)sBh + (w8 << 10));
      else         gl2lds16(w1l + go, (char*)sBl + (w8 << 10));
    }
    // ---- stage A (f32 -> fp16 hi/lo in-register -> LDS), 2 rows per thread
    int f = gk >> 9, off = gk & 255;
    const float* xb = ((gk >> 8) & 1) ? varp : meanp;
#pragma unroll
    for (int p = 0; p < 2; ++p) {
      int row = ar + (p << 7);
      const float4 v = *(const float4*)(xb + ((size_t)(bm + row) * NF + f) * ND + off + (ac4 << 2));
      f16 h0 = (f16)v.x, h1 = (f16)v.y, h2 = (f16)v.z, h3 = (f16)v.w;
      f16x4 hv = {h0, h1, h2, h3};
      f16x4 lv = {(f16)((v.x - (float)h0) * LSCALE), (f16)((v.y - (float)h1) * LSCALE),
                  (f16)((v.z - (float)h2) * LSCALE), (f16)((v.w - (float)h3) * LSCALE)};
      int byte = (row << 6) + (swz4(row, ac4 >> 1) << 4) + ((ac4 & 1) << 3);
      *(f16x4*)((char*)sAh + byte) = hv;
      *(f16x4*)((char*)sAl + byte) = lv;
    }
    __syncthreads();
    // ---- compute: wave (wr,wc) owns rows [wr*32,+32) x cols [wc*64,+64)
    f16x8 ah[2], al[2], bh[4], bl[4];
#pragma unroll
    for (int m = 0; m < 2; ++m) {
      int row = (wr << 5) + (m << 4) + lr;
      int byte = (row << 6) + (swz4(row, lk) << 4);
      ah[m] = *(const f16x8*)((const char*)sAh + byte);
      al[m] = *(const f16x8*)((const char*)sAl + byte);
    }
#pragma unroll
    for (int n = 0; n < 4; ++n) {
      int col = (wc << 6) + (n << 4) + lr;
      int byte = (col << 6) + (swz4(col, lk) << 4);
      bh[n] = *(const f16x8*)((const char*)sBh + byte);
      bl[n] = *(const f16x8*)((const char*)sBl + byte);
    }
#pragma unroll
    for (int m = 0; m < 2; ++m)
#pragma unroll
      for (int n = 0; n < 4; ++n) {
        acc0[m][n] = __builtin_amdgcn_mfma_f32_16x16x32_f16(ah[m], bh[n], acc0[m][n], 0, 0, 0);
        acc1[m][n] = __builtin_amdgcn_mfma_f32_16x16x32_f16(ah[m], bl[n], acc1[m][n], 0, 0, 0);
        acc1[m][n] = __builtin_amdgcn_mfma_f32_16x16x32_f16(al[m], bh[n], acc1[m][n], 0, 0, 0);
      }
    __syncthreads();
  }
  float* po = partial + (size_t)chunk * NB * ND;
#pragma unroll
  for (int m = 0; m < 2; ++m)
#pragma unroll
    for (int n = 0; n < 4; ++n)
#pragma unroll
      for (int r = 0; r < 4; ++r)
        po[(size_t)(bm + (wr << 5) + (m << 4) + (lk << 2) + r) * ND + bn + (wc << 6) + (n << 4) + lr] =
            (acc0[m][n][r] + acc1[m][n][r] * INV_LS) * INV_WS;
}

__device__ __forceinline__ double block_sum_f64(double v, double* sred) {
#pragma unroll
  for (int m = 32; m >= 1; m >>= 1) v += __shfl_xor(v, m);
  __syncthreads();
  if ((threadIdx.x & 63) == 0) sred[threadIdx.x >> 6] = v;
  __syncthreads();
  return sred[0] + sred[1] + sred[2] + sred[3];
}

// ---------------- reduce + f64 GELU/LN/selection; flag row iff cut-gap a[85]-a[86] < M ----------------
__global__ __launch_bounds__(256) void reduce_ln_kwta(const float* __restrict__ partial, const float* __restrict__ b1,
                                                      const float* __restrict__ gamma, const float* __restrict__ beta,
                                                      f16* __restrict__ hh, f16* __restrict__ hl,
                                                      int* __restrict__ flags) {
  int b = blockIdx.x, d = threadIdx.x;
  double s = 0.0;
#pragma unroll
  for (int c = 0; c < 32; ++c) s += (double)partial[((size_t)c * NB + b) * ND + d];
  s += (double)b1[d];
  double g = 0.5 * s * (1.0 + erf(s * 0.70710678118654752440));
  __shared__ double sredd[4];
  double mu = block_sum_f64(g, sredd) * (1.0 / 256.0);
  double dv = g - mu;
  double var = block_sum_f64(dv * dv, sredd) * (1.0 / 256.0);
  double hn = dv * (1.0 / sqrt(var + 1e-3)) * (double)gamma[d] + (double)beta[d];
  double a = fabs(hn);
  __shared__ double as_[256];
  as_[d] = a;
  __syncthreads();
  int cnt_ex = 0;
  for (int j = 0; j < 256; ++j) {
    double aj = as_[j];
    cnt_ex += ((aj > a) || (aj == a && j < d)) ? 1 : 0;
  }
  __shared__ double a85, a86;
  if (cnt_ex == KWIN - 1) a85 = a;
  if (cnt_ex == KWIN) a86 = a;
  __syncthreads();
  const double M = 2e-5;  // >=20 sigma of fp16x3 GEMM noise in a-units
  if (d == 0 && (a85 - a86 < M)) {
    int slot = atomicAdd(&flags[0], 1);
    if (slot < MAXFIX) flags[1 + slot] = b;
  }
  float hv = (cnt_ex < KWIN) ? (float)hn : 0.f;
  f16 h = (f16)hv;
  size_t o = (size_t)b * ND + d;
  hh[o] = h;
  hl[o] = (f16)((hv - (float)h) * LSCALE);
}

// ---------------- fixup pass 1: exact GEMV for flagged rows (two-prod -> f64 accum) ----------------
__global__ __launch_bounds__(256) void fixup_gemv(const float* __restrict__ meanp, const float* __restrict__ varp,
                                                  const float* __restrict__ W1, const int* __restrict__ flags,
                                                  double* __restrict__ p64) {
  int nf = flags[0]; if (nf > MAXFIX) nf = MAXFIX;
  int slot = blockIdx.x >> 6;
  int kb = blockIdx.x & (FKB - 1);
  if (slot >= nf) return;
  int r = flags[1 + slot];
  int t = threadIdx.x;
  __shared__ float xs[512];
  int k0 = kb << 9;
  for (int i = t; i < 512; i += 256) {
    const float* xb = (i & 256) ? varp : meanp;
    xs[i] = xb[(((size_t)r * NF + kb) << 8) + (i & 255)];
  }
  __syncthreads();
  double accp0 = 0.0, accp1 = 0.0, acce0 = 0.0, acce1 = 0.0;
  const float* wcol = W1 + (size_t)k0 * ND + t;
#pragma unroll 8
  for (int i = 0; i < 512; i += 2) {
    float x0 = xs[i], w0 = wcol[(size_t)i * ND];
    float x1 = xs[i + 1], w1 = wcol[(size_t)(i + 1) * ND];
    float p0 = x0 * w0, p1 = x1 * w1;
    float e0 = fmaf(x0, w0, -p0), e1 = fmaf(x1, w1, -p1);
    accp0 += (double)p0;
    accp1 += (double)p1;
    acce0 += (double)e0;
    acce1 += (double)e1;
  }
  p64[((size_t)slot * FKB + kb) * ND + t] = (accp0 + accp1) + (acce0 + acce1);
}

// ---------------- fixup pass 2: f64 GELU + LN + exact kWTA for flagged rows ----------------
__global__ __launch_bounds__(256) void fixup_ln_kwta(const double* __restrict__ p64, const float* __restrict__ b1,
                                                     const float* __restrict__ gamma, const float* __restrict__ beta,
                                                     const int* __restrict__ flags,
                                                     f16* __restrict__ hh, f16* __restrict__ hl) {
  int nf = flags[0]; if (nf > MAXFIX) nf = MAXFIX;
  int slot = blockIdx.x;
  if (slot >= nf) return;
  int r = flags[1 + slot];
  int d = threadIdx.x;
  double s = 0.0;
#pragma unroll
  for (int kb = 0; kb < FKB; ++kb) s += p64[((size_t)slot * FKB + kb) * ND + d];
  s += (double)b1[d];
  double g = 0.5 * s * (1.0 + erf(s * 0.70710678118654752440));
  __shared__ double sredd[4];
  double mu = block_sum_f64(g, sredd) * (1.0 / 256.0);
  double dv = g - mu;
  double var = block_sum_f64(dv * dv, sredd) * (1.0 / 256.0);
  double hn = dv * (1.0 / sqrt(var + 1e-3)) * (double)gamma[d] + (double)beta[d];
  double a = fabs(hn);
  __shared__ double as_[256];
  as_[d] = a;
  __syncthreads();
  int cnt = 0;
  for (int j = 0; j < 256; ++j) {
    double aj = as_[j];
    cnt += ((aj > a) || (aj == a && j < d)) ? 1 : 0;
  }
  double hvd = (cnt < KWIN) ? hn : 0.0;
  float hf = (float)hvd;
  f16 h = (f16)hf;
  size_t o = (size_t)r * ND + d;
  hh[o] = h;
  hl[o] = (f16)((hf - (float)h) * LSCALE);
}

// ---------------- GEMM2: out = tanh(h @ W2 + b2), fp16x3 dual-acc; fast exp-based tanh ----------------
__global__ __launch_bounds__(256, 2) void gemm2_kernel(const f16* __restrict__ hh, const f16* __restrict__ hl,
                                                       const f16* __restrict__ w2h, const f16* __restrict__ w2l,
                                                       const float* __restrict__ b2, float* __restrict__ outp) {
  __shared__ alignas(16) f16 sAh[128 * 64], sAl[128 * 64];
  __shared__ alignas(16) f16 sBh[128 * 64], sBl[128 * 64];
  int t = threadIdx.x;
  int bm = (blockIdx.x & 7) << 7;
  int bn = (blockIdx.x >> 3) << 7;
  int wid = t >> 6, lane = t & 63, lr = lane & 15, lk = lane >> 4;
  int wr = wid >> 1, wc = wid & 1;
  f32x4 acc0[4][4] = {};
  f32x4 acc1[4][4] = {};
  int amr = t >> 3, aslot = t & 7;

  for (int s = 0; s < 4; ++s) {
    int k0 = s << 6;
#pragma unroll
    for (int i = 0; i < 4; ++i) {
      int m = (i << 5) + amr;
      int ks = swz8(m, aslot) << 3;
      size_t goa = (size_t)(bm + m) * ND + k0 + ks;
      size_t gob = (size_t)(bn + m) * ND + k0 + ks;
      gl2lds16(hh + goa, (char*)sAh + (i << 12) + (wid << 10));
      gl2lds16(hl + goa, (char*)sAl + (i << 12) + (wid << 10));
      gl2lds16(w2h + gob, (char*)sBh + (i << 12) + (wid << 10));
      gl2lds16(w2l + gob, (char*)sBl + (i << 12) + (wid << 10));
    }
    __syncthreads();
#pragma unroll
    for (int k2 = 0; k2 < 2; ++k2) {
      int slot = (k2 << 2) + lk;
      f16x8 ah[4], al[4], bh[4], bl[4];
#pragma unroll
      for (int m = 0; m < 4; ++m) {
        int row = (wr << 6) + (m << 4) + lr;
        int byte = (row << 7) + (swz8(row, slot) << 4);
        ah[m] = *(const f16x8*)((const char*)sAh + byte);
        al[m] = *(const f16x8*)((const char*)sAl + byte);
      }
#pragma unroll
      for (int n = 0; n < 4; ++n) {
        int col = (wc << 6) + (n << 4) + lr;
        int byte = (col << 7) + (swz8(col, slot) << 4);
        bh[n] = *(const f16x8*)((const char*)sBh + byte);
        bl[n] = *(const f16x8*)((const char*)sBl + byte);
      }
#pragma unroll
      for (int m = 0; m < 4; ++m)
#pragma unroll
        for (int n = 0; n < 4; ++n) {
          acc0[m][n] = __builtin_amdgcn_mfma_f32_16x16x32_f16(ah[m], bh[n], acc0[m][n], 0, 0, 0);
          acc1[m][n] = __builtin_amdgcn_mfma_f32_16x16x32_f16(ah[m], bl[n], acc1[m][n], 0, 0, 0);
          acc1[m][n] = __builtin_amdgcn_mfma_f32_16x16x32_f16(al[m], bh[n], acc1[m][n], 0, 0, 0);
        }
    }
    __syncthreads();
  }
#pragma unroll
  for (int m = 0; m < 4; ++m)
#pragma unroll
    for (int n = 0; n < 4; ++n)
#pragma unroll
      for (int r = 0; r < 4; ++r) {
        int row = bm + (wr << 6) + (m << 4) + (lk << 2) + r;
        int col = bn + (wc << 6) + (n << 4) + lr;
        float val = (acc0[m][n][r] + acc1[m][n][r] * INV_LS) * INV_WS + b2[col];
        float av = fabsf(val);
        float e = __expf(-2.0f * av);
        float rr = (1.0f - e) / (1.0f + e);
        outp[(size_t)row * OUTC + col] = copysignf(rr, val);
      }
}

extern "C" void kernel_launch(void* const* d_in, const int* in_sizes, int n_in,
                              void* d_out, int out_size, void* d_ws, size_t ws_size,
                              hipStream_t stream) {
  (void)in_sizes; (void)n_in; (void)out_size; (void)ws_size;
  const float* meanp = (const float*)d_in[0];
  const float* varp  = (const float*)d_in[1];
  const float* W1    = (const float*)d_in[2];
  const float* b1    = (const float*)d_in[3];
  const float* gamma = (const float*)d_in[4];
  const float* beta  = (const float*)d_in[5];
  const float* W2    = (const float*)d_in[6];
  const float* b2    = (const float*)d_in[7];
  float* outp = (float*)d_out;
  char* ws = (char*)d_ws;

  f16* w1h = (f16*)(ws);                              // 16 MiB: [256][32768]
  f16* w1l = (f16*)(ws + ((size_t)16 << 20));         // 16 MiB
  f16* w2h = (f16*)(ws + ((size_t)32 << 20));         // 4 MiB: [8192][256]
  f16* w2l = (f16*)(ws + ((size_t)36 << 20));         // 4 MiB
  float* partial = (float*)(ws + ((size_t)40 << 20)); // 32 MiB: [32][1024][256]
  double* p64 = (double*)(ws + ((size_t)40 << 20));   // 4.2 MiB, aliases partial (consumed before use)
  f16* hh = (f16*)(ws + ((size_t)72 << 20));          // 512 KiB
  f16* hl = (f16*)(ws + ((size_t)72 << 20) + ((size_t)512 << 10)); // 512 KiB
  int* flags = (int*)(ws + ((size_t)73 << 20));       // nflag + rows[MAXFIX]

  hipMemsetAsync(flags, 0, (1 + MAXFIX) * sizeof(int), stream);
  transpose_split<<<2048, 256, 0, stream>>>(W1, w1h, w1l, INDIM, ND);
  transpose_split<<<512, 256, 0, stream>>>(W2, w2h, w2l, ND, OUTC);
  gemm1_kernel<<<256, 1024, 0, stream>>>(meanp, varp, w1h, w1l, partial);
  reduce_ln_kwta<<<NB, 256, 0, stream>>>(partial, b1, gamma, beta, hh, hl, flags);
  fixup_gemv<<<MAXFIX * FKB, 256, 0, stream>>>(meanp, varp, W1, flags, p64);
  fixup_ln_kwta<<<MAXFIX, 256, 0, stream>>>(p64, b1, gamma, beta, flags, hh, hl);
  gemm2_kernel<<<512, 256, 0, stream>>>(hh, hl, w2h, w2l, b2, outp);
}

// Round 16
// 185.372 us; speedup vs baseline: 1.0843x; 1.0843x over previous
//
#include <hip/hip_runtime.h>

typedef _Float16 f16;
typedef f16 f16x4 __attribute__((ext_vector_type(4)));
typedef f16 f16x8 __attribute__((ext_vector_type(8)));
typedef float f32x4 __attribute__((ext_vector_type(4)));

#define NB 1024
#define NF 64
#define ND 256
#define KWIN 85
#define INDIM 32768
#define OUTC 8192
#define MAXFIX 32
#define FKB 64  // k-chunks per flagged row in fixup pass 1 (512 k each)
// W pre-scaled by 256; lo-parts scaled by 2048; undone in f32 epilogues.
#define WSCALE 256.0f
#define LSCALE 2048.0f
#define INV_WS (1.0f / 256.0f)
#define INV_LS (1.0f / 2048.0f)

__device__ __forceinline__ int swz4(int row, int slot) { return slot ^ ((row ^ (row >> 2)) & 3); }
__device__ __forceinline__ int swz8(int row, int slot) { return slot ^ ((row ^ (row >> 3)) & 7); }

__device__ __forceinline__ void gl2lds16(const void* g, void* l) {
  __builtin_amdgcn_global_load_lds((const __attribute__((address_space(1))) void*)g,
                                   (__attribute__((address_space(3))) void*)l, 16, 0, 0);
}

// ---------------- transpose + fp16 hi/lo-scaled split: dst[c][r] = split(src[r][c]*256) ----------------
__global__ __launch_bounds__(256) void transpose_split(const float* __restrict__ src,
                                                       f16* __restrict__ dhi, f16* __restrict__ dlo,
                                                       int R, int C) {
  __shared__ float tile[64][65];
  int t = threadIdx.x;
  int tiles_c = C >> 6;
  int tr = blockIdx.x / tiles_c, tc = blockIdx.x - tr * tiles_c;
  size_t r0 = (size_t)tr << 6;
  int c0 = tc << 6;
  int rr = t >> 4, cc = (t & 15) << 2;
#pragma unroll
  for (int p = 0; p < 4; ++p) {
    const float4 v = *(const float4*)(src + (r0 + (p << 4) + rr) * C + c0 + cc);
    tile[(p << 4) + rr][cc + 0] = v.x;
    tile[(p << 4) + rr][cc + 1] = v.y;
    tile[(p << 4) + rr][cc + 2] = v.z;
    tile[(p << 4) + rr][cc + 3] = v.w;
  }
  __syncthreads();
  int n = t >> 2, kq = t & 3;
  alignas(16) f16 hv[16];
  alignas(16) f16 lv[16];
#pragma unroll
  for (int e = 0; e < 16; ++e) {
    float x = tile[(kq << 4) + e][n] * WSCALE;
    f16 h = (f16)x;
    hv[e] = h;
    lv[e] = (f16)((x - (float)h) * LSCALE);
  }
  size_t ob = (size_t)(c0 + n) * (size_t)R + r0 + (kq << 4);
  *(f16x8*)(dhi + ob)     = *(const f16x8*)&hv[0];
  *(f16x8*)(dhi + ob + 8) = *(const f16x8*)&hv[8];
  *(f16x8*)(dlo + ob)     = *(const f16x8*)&lv[0];
  *(f16x8*)(dlo + ob + 8) = *(const f16x8*)&lv[8];
}

// ---------------- GEMM1: r14 tile (BM=128 x BN=128, 512 thr, 2 blk/CU) + 2-phase schedule ----------------
// partial[chunk] = x[:, chunk*1024:+1024] @ W1[chunk rows]; fp16x3 dual-acc.
// T3-minimum: double-buffered LDS, STAGE(next) issued BEFORE compute(cur), ONE __syncthreads per tile
// (syncthreads = vmcnt(0)+lgkm(0) drain + barrier; stage has a full compute phase to land).
// A staged via 2-ahead register fly buffer so f32 load latency also hides under compute.
__global__ __launch_bounds__(512, 4) void gemm1_kernel(const float* __restrict__ meanp, const float* __restrict__ varp,
                                                       const f16* __restrict__ w1h, const f16* __restrict__ w1l,
                                                       float* __restrict__ partial) {
  __shared__ alignas(16) f16 sAh[2][128 * 32], sAl[2][128 * 32];  // 8 KB per buf
  __shared__ alignas(16) f16 sBh[2][128 * 32], sBl[2][128 * 32];  // 8 KB per buf (64 KB total)
  int t = threadIdx.x;
  int chunk = blockIdx.x & 31;
  int nb = (blockIdx.x >> 5) & 1;
  int rb = blockIdx.x >> 6;
  int bm = rb << 7, bn = nb << 7;
  int wid = t >> 6, lane = t & 63, lr = lane & 15, lk = lane >> 4;
  int wr = wid >> 1, wc = wid & 1;  // 4 row-groups x 2 col-groups; wave tile 32x64
  f32x4 acc0[2][4] = {};
  f32x4 acc1[2][4] = {};
  int ar = t >> 3, ac4 = t & 7;    // A: rows ar, ar+64; 8 k-slots
  int bnr = t >> 2, bslot = t & 3; // B: 128 cols x 4 slot-pairs (1 gl2lds16/thread/buffer)

  float4 fly[2];  // in-flight f32 A rows for tile (kk+1) at loop top

  auto STAGE_B = [&](int kkv, int buf) {
    int gk = (chunk << 10) + ((kkv & 31) << 5);
    size_t go = (size_t)(bn + bnr) * INDIM + (size_t)gk + (size_t)(swz4(bnr, bslot) << 3);
    gl2lds16(w1h + go, (char*)&sBh[buf][0] + (wid << 10));
    gl2lds16(w1l + go, (char*)&sBl[buf][0] + (wid << 10));
  };
  auto LOAD_A = [&](int kkv) {
    int gk = (chunk << 10) + ((kkv & 31) << 5);
    int f = gk >> 9, off = (gk & 255) + (ac4 << 2);
    const float* xb = ((gk >> 8) & 1) ? varp : meanp;
#pragma unroll
    for (int p = 0; p < 2; ++p) {
      int row = ar + (p << 6);
      fly[p] = *(const float4*)(xb + ((size_t)(bm + row) * NF + f) * ND + off);
    }
  };
  auto WRITE_A = [&](int buf) {
#pragma unroll
    for (int p = 0; p < 2; ++p) {
      int row = ar + (p << 6);
      float4 v = fly[p];
      f16 h0 = (f16)v.x, h1 = (f16)v.y, h2 = (f16)v.z, h3 = (f16)v.w;
      f16x4 hv = {h0, h1, h2, h3};
      f16x4 lv = {(f16)((v.x - (float)h0) * LSCALE), (f16)((v.y - (float)h1) * LSCALE),
                  (f16)((v.z - (float)h2) * LSCALE), (f16)((v.w - (float)h3) * LSCALE)};
      int byte = (row << 6) + (swz4(row, ac4 >> 1) << 4) + ((ac4 & 1) << 3);
      *(f16x4*)((char*)&sAh[buf][0] + byte) = hv;
      *(f16x4*)((char*)&sAl[buf][0] + byte) = lv;
    }
  };

  // prologue: tile 0 fully staged into buf0; fly = f32 A(1)
  STAGE_B(0, 0);
  LOAD_A(0);
  WRITE_A(0);
  LOAD_A(1);
  __syncthreads();

  int cur = 0;
  for (int kk = 0; kk < 32; ++kk) {
    int nxt = cur ^ 1;
    // ---- stage tile kk+1 into buf[nxt] (issued before compute; lands under it)
    STAGE_B(kk + 1, nxt);
    WRITE_A(nxt);     // converts fly = A(kk+1), ds_write (loads issued an iter ago -> ready)
    LOAD_A(kk + 2);   // issue f32 A(kk+2), consumed next iter (wraps harmlessly)
    // ---- compute tile kk from buf[cur]
    f16x8 ah[2], al[2], bh[4], bl[4];
#pragma unroll
    for (int m = 0; m < 2; ++m) {
      int row = (wr << 5) + (m << 4) + lr;
      int byte = (row << 6) + (swz4(row, lk) << 4);
      ah[m] = *(const f16x8*)((const char*)&sAh[cur][0] + byte);
      al[m] = *(const f16x8*)((const char*)&sAl[cur][0] + byte);
    }
#pragma unroll
    for (int n = 0; n < 4; ++n) {
      int col = (wc << 6) + (n << 4) + lr;
      int byte = (col << 6) + (swz4(col, lk) << 4);
      bh[n] = *(const f16x8*)((const char*)&sBh[cur][0] + byte);
      bl[n] = *(const f16x8*)((const char*)&sBl[cur][0] + byte);
    }
#pragma unroll
    for (int m = 0; m < 2; ++m)
#pragma unroll
      for (int n = 0; n < 4; ++n) {
        acc0[m][n] = __builtin_amdgcn_mfma_f32_16x16x32_f16(ah[m], bh[n], acc0[m][n], 0, 0, 0);
        acc1[m][n] = __builtin_amdgcn_mfma_f32_16x16x32_f16(ah[m], bl[n], acc1[m][n], 0, 0, 0);
        acc1[m][n] = __builtin_amdgcn_mfma_f32_16x16x32_f16(al[m], bh[n], acc1[m][n], 0, 0, 0);
      }
    // one barrier per tile: drains this wave's gl2lds/ds_write (vmcnt0+lgkm0) then syncs
    __syncthreads();
    cur = nxt;
  }
  float* po = partial + (size_t)chunk * NB * ND;
#pragma unroll
  for (int m = 0; m < 2; ++m)
#pragma unroll
    for (int n = 0; n < 4; ++n)
#pragma unroll
      for (int r = 0; r < 4; ++r)
        po[(size_t)(bm + (wr << 5) + (m << 4) + (lk << 2) + r) * ND + bn + (wc << 6) + (n << 4) + lr] =
            (acc0[m][n][r] + acc1[m][n][r] * INV_LS) * INV_WS;
}

__device__ __forceinline__ double block_sum_f64(double v, double* sred) {
#pragma unroll
  for (int m = 32; m >= 1; m >>= 1) v += __shfl_xor(v, m);
  __syncthreads();
  if ((threadIdx.x & 63) == 0) sred[threadIdx.x >> 6] = v;
  __syncthreads();
  return sred[0] + sred[1] + sred[2] + sred[3];
}

// ---------------- reduce + f64 GELU/LN/selection; flag row iff cut-gap a[85]-a[86] < M ----------------
__global__ __launch_bounds__(256) void reduce_ln_kwta(const float* __restrict__ partial, const float* __restrict__ b1,
                                                      const float* __restrict__ gamma, const float* __restrict__ beta,
                                                      f16* __restrict__ hh, f16* __restrict__ hl,
                                                      int* __restrict__ flags) {
  int b = blockIdx.x, d = threadIdx.x;
  double s = 0.0;
#pragma unroll
  for (int c = 0; c < 32; ++c) s += (double)partial[((size_t)c * NB + b) * ND + d];
  s += (double)b1[d];
  double g = 0.5 * s * (1.0 + erf(s * 0.70710678118654752440));
  __shared__ double sredd[4];
  double mu = block_sum_f64(g, sredd) * (1.0 / 256.0);
  double dv = g - mu;
  double var = block_sum_f64(dv * dv, sredd) * (1.0 / 256.0);
  double hn = dv * (1.0 / sqrt(var + 1e-3)) * (double)gamma[d] + (double)beta[d];
  double a = fabs(hn);
  __shared__ double as_[256];
  as_[d] = a;
  __syncthreads();
  int cnt_ex = 0;
  for (int j = 0; j < 256; ++j) {
    double aj = as_[j];
    cnt_ex += ((aj > a) || (aj == a && j < d)) ? 1 : 0;
  }
  __shared__ double a85, a86;
  if (cnt_ex == KWIN - 1) a85 = a;
  if (cnt_ex == KWIN) a86 = a;
  __syncthreads();
  const double M = 2e-5;  // >=20 sigma of fp16x3 GEMM noise in a-units
  if (d == 0 && (a85 - a86 < M)) {
    int slot = atomicAdd(&flags[0], 1);
    if (slot < MAXFIX) flags[1 + slot] = b;
  }
  float hv = (cnt_ex < KWIN) ? (float)hn : 0.f;
  f16 h = (f16)hv;
  size_t o = (size_t)b * ND + d;
  hh[o] = h;
  hl[o] = (f16)((hv - (float)h) * LSCALE);
}

// ---------------- fixup pass 1: exact GEMV for flagged rows (two-prod -> f64 accum) ----------------
__global__ __launch_bounds__(256) void fixup_gemv(const float* __restrict__ meanp, const float* __restrict__ varp,
                                                  const float* __restrict__ W1, const int* __restrict__ flags,
                                                  double* __restrict__ p64) {
  int nf = flags[0]; if (nf > MAXFIX) nf = MAXFIX;
  int slot = blockIdx.x >> 6;
  int kb = blockIdx.x & (FKB - 1);
  if (slot >= nf) return;
  int r = flags[1 + slot];
  int t = threadIdx.x;
  __shared__ float xs[512];
  int k0 = kb << 9;
  for (int i = t; i < 512; i += 256) {
    const float* xb = (i & 256) ? varp : meanp;
    xs[i] = xb[(((size_t)r * NF + kb) << 8) + (i & 255)];
  }
  __syncthreads();
  double accp0 = 0.0, accp1 = 0.0, acce0 = 0.0, acce1 = 0.0;
  const float* wcol = W1 + (size_t)k0 * ND + t;
#pragma unroll 8
  for (int i = 0; i < 512; i += 2) {
    float x0 = xs[i], w0 = wcol[(size_t)i * ND];
    float x1 = xs[i + 1], w1 = wcol[(size_t)(i + 1) * ND];
    float p0 = x0 * w0, p1 = x1 * w1;
    float e0 = fmaf(x0, w0, -p0), e1 = fmaf(x1, w1, -p1);
    accp0 += (double)p0;
    accp1 += (double)p1;
    acce0 += (double)e0;
    acce1 += (double)e1;
  }
  p64[((size_t)slot * FKB + kb) * ND + t] = (accp0 + accp1) + (acce0 + acce1);
}

// ---------------- fixup pass 2: f64 GELU + LN + exact kWTA for flagged rows ----------------
__global__ __launch_bounds__(256) void fixup_ln_kwta(const double* __restrict__ p64, const float* __restrict__ b1,
                                                     const float* __restrict__ gamma, const float* __restrict__ beta,
                                                     const int* __restrict__ flags,
                                                     f16* __restrict__ hh, f16* __restrict__ hl) {
  int nf = flags[0]; if (nf > MAXFIX) nf = MAXFIX;
  int slot = blockIdx.x;
  if (slot >= nf) return;
  int r = flags[1 + slot];
  int d = threadIdx.x;
  double s = 0.0;
#pragma unroll
  for (int kb = 0; kb < FKB; ++kb) s += p64[((size_t)slot * FKB + kb) * ND + d];
  s += (double)b1[d];
  double g = 0.5 * s * (1.0 + erf(s * 0.70710678118654752440));
  __shared__ double sredd[4];
  double mu = block_sum_f64(g, sredd) * (1.0 / 256.0);
  double dv = g - mu;
  double var = block_sum_f64(dv * dv, sredd) * (1.0 / 256.0);
  double hn = dv * (1.0 / sqrt(var + 1e-3)) * (double)gamma[d] + (double)beta[d];
  double a = fabs(hn);
  __shared__ double as_[256];
  as_[d] = a;
  __syncthreads();
  int cnt = 0;
  for (int j = 0; j < 256; ++j) {
    double aj = as_[j];
    cnt += ((aj > a) || (aj == a && j < d)) ? 1 : 0;
  }
  double hvd = (cnt < KWIN) ? hn : 0.0;
  float hf = (float)hvd;
  f16 h = (f16)hf;
  size_t o = (size_t)r * ND + d;
  hh[o] = h;
  hl[o] = (f16)((hf - (float)h) * LSCALE);
}

// ---------------- GEMM2: out = tanh(h @ W2 + b2), fp16x3 dual-acc; fast exp-based tanh ----------------
__global__ __launch_bounds__(256, 2) void gemm2_kernel(const f16* __restrict__ hh, const f16* __restrict__ hl,
                                                       const f16* __restrict__ w2h, const f16* __restrict__ w2l,
                                                       const float* __restrict__ b2, float* __restrict__ outp) {
  __shared__ alignas(16) f16 sAh[128 * 64], sAl[128 * 64];
  __shared__ alignas(16) f16 sBh[128 * 64], sBl[128 * 64];
  int t = threadIdx.x;
  int bm = (blockIdx.x & 7) << 7;
  int bn = (blockIdx.x >> 3) << 7;
  int wid = t >> 6, lane = t & 63, lr = lane & 15, lk = lane >> 4;
  int wr = wid >> 1, wc = wid & 1;
  f32x4 acc0[4][4] = {};
  f32x4 acc1[4][4] = {};
  int amr = t >> 3, aslot = t & 7;

  for (int s = 0; s < 4; ++s) {
    int k0 = s << 6;
#pragma unroll
    for (int i = 0; i < 4; ++i) {
      int m = (i << 5) + amr;
      int ks = swz8(m, aslot) << 3;
      size_t goa = (size_t)(bm + m) * ND + k0 + ks;
      size_t gob = (size_t)(bn + m) * ND + k0 + ks;
      gl2lds16(hh + goa, (char*)sAh + (i << 12) + (wid << 10));
      gl2lds16(hl + goa, (char*)sAl + (i << 12) + (wid << 10));
      gl2lds16(w2h + gob, (char*)sBh + (i << 12) + (wid << 10));
      gl2lds16(w2l + gob, (char*)sBl + (i << 12) + (wid << 10));
    }
    __syncthreads();
#pragma unroll
    for (int k2 = 0; k2 < 2; ++k2) {
      int slot = (k2 << 2) + lk;
      f16x8 ah[4], al[4], bh[4], bl[4];
#pragma unroll
      for (int m = 0; m < 4; ++m) {
        int row = (wr << 6) + (m << 4) + lr;
        int byte = (row << 7) + (swz8(row, slot) << 4);
        ah[m] = *(const f16x8*)((const char*)sAh + byte);
        al[m] = *(const f16x8*)((const char*)sAl + byte);
      }
#pragma unroll
      for (int n = 0; n < 4; ++n) {
        int col = (wc << 6) + (n << 4) + lr;
        int byte = (col << 7) + (swz8(col, slot) << 4);
        bh[n] = *(const f16x8*)((const char*)sBh + byte);
        bl[n] = *(const f16x8*)((const char*)sBl + byte);
      }
#pragma unroll
      for (int m = 0; m < 4; ++m)
#pragma unroll
        for (int n = 0; n < 4; ++n) {
          acc0[m][n] = __builtin_amdgcn_mfma_f32_16x16x32_f16(ah[m], bh[n], acc0[m][n], 0, 0, 0);
          acc1[m][n] = __builtin_amdgcn_mfma_f32_16x16x32_f16(ah[m], bl[n], acc1[m][n], 0, 0, 0);
          acc1[m][n] = __builtin_amdgcn_mfma_f32_16x16x32_f16(al[m], bh[n], acc1[m][n], 0, 0, 0);
        }
    }
    __syncthreads();
  }
#pragma unroll
  for (int m = 0; m < 4; ++m)
#pragma unroll
    for (int n = 0; n < 4; ++n)
#pragma unroll
      for (int r = 0; r < 4; ++r) {
        int row = bm + (wr << 6) + (m << 4) + (lk << 2) + r;
        int col = bn + (wc << 6) + (n << 4) + lr;
        float val = (acc0[m][n][r] + acc1[m][n][r] * INV_LS) * INV_WS + b2[col];
        float av = fabsf(val);
        float e = __expf(-2.0f * av);
        float rr = (1.0f - e) / (1.0f + e);
        outp[(size_t)row * OUTC + col] = copysignf(rr, val);
      }
}

extern "C" void kernel_launch(void* const* d_in, const int* in_sizes, int n_in,
                              void* d_out, int out_size, void* d_ws, size_t ws_size,
                              hipStream_t stream) {
  (void)in_sizes; (void)n_in; (void)out_size; (void)ws_size;
  const float* meanp = (const float*)d_in[0];
  const float* varp  = (const float*)d_in[1];
  const float* W1    = (const float*)d_in[2];
  const float* b1    = (const float*)d_in[3];
  const float* gamma = (const float*)d_in[4];
  const float* beta  = (const float*)d_in[5];
  const float* W2    = (const float*)d_in[6];
  const float* b2    = (const float*)d_in[7];
  float* outp = (float*)d_out;
  char* ws = (char*)d_ws;

  f16* w1h = (f16*)(ws);                              // 16 MiB: [256][32768]
  f16* w1l = (f16*)(ws + ((size_t)16 << 20));         // 16 MiB
  f16* w2h = (f16*)(ws + ((size_t)32 << 20));         // 4 MiB: [8192][256]
  f16* w2l = (f16*)(ws + ((size_t)36 << 20));         // 4 MiB
  float* partial = (float*)(ws + ((size_t)40 << 20)); // 32 MiB: [32][1024][256]
  double* p64 = (double*)(ws + ((size_t)40 << 20));   // 4.2 MiB, aliases partial (consumed before use)
  f16* hh = (f16*)(ws + ((size_t)72 << 20));          // 512 KiB
  f16* hl = (f16*)(ws + ((size_t)72 << 20) + ((size_t)512 << 10)); // 512 KiB
  int* flags = (int*)(ws + ((size_t)73 << 20));       // nflag + rows[MAXFIX]

  hipMemsetAsync(flags, 0, (1 + MAXFIX) * sizeof(int), stream);
  transpose_split<<<2048, 256, 0, stream>>>(W1, w1h, w1l, INDIM, ND);
  transpose_split<<<512, 256, 0, stream>>>(W2, w2h, w2l, ND, OUTC);
  gemm1_kernel<<<512, 512, 0, stream>>>(meanp, varp, w1h, w1l, partial);
  reduce_ln_kwta<<<NB, 256, 0, stream>>>(partial, b1, gamma, beta, hh, hl, flags);
  fixup_gemv<<<MAXFIX * FKB, 256, 0, stream>>>(meanp, varp, W1, flags, p64);
  fixup_ln_kwta<<<MAXFIX, 256, 0, stream>>>(p64, b1, gamma, beta, flags, hh, hl);
  gemm2_kernel<<<512, 256, 0, stream>>>(hh, hl, w2h, w2l, b2, outp);
}